// Round 4
// baseline (570.320 us; speedup 1.0000x reference)
//
#include <hip/hip_runtime.h>
#include <hip/hip_bf16.h>

typedef short short8 __attribute__((ext_vector_type(8)));
typedef float floatx4 __attribute__((ext_vector_type(4)));

#define HP 168   // h1 LDS pitch (shorts): 336 B rows, 16B-aligned; stride 84 words ≡ 20 mod 32 -> 2-way only

__device__ __forceinline__ unsigned short f2bf(float f) {
    __hip_bfloat16 h = __float2bfloat16(f);
    return __builtin_bit_cast(unsigned short, h);
}
__device__ __forceinline__ float bf2f(unsigned short s) {
    __hip_bfloat16 h = __builtin_bit_cast(__hip_bfloat16, s);
    return __bfloat162float(h);
}

// Pack Wc = [w1; wt] (320x320) into B-fragment order for mfma_f32_16x16x32_bf16.
// elem j of lane l for (t,kb): n = t*16+(l&15), k = kb*32+(l>>4)*8+j; flat (((t*10+kb)*64+l)*8+j)
__global__ void pack_wc(const float* __restrict__ w1, const float* __restrict__ wt,
                        unsigned short* __restrict__ dst) {
    int i = blockIdx.x * 256 + threadIdx.x;
    if (i >= 320 * 320) return;
    int j = i & 7;
    int lane = (i >> 3) & 63;
    int r = i >> 9;
    int kb = r % 10;
    int t = r / 10;
    int n = t * 16 + (lane & 15);
    int k = kb * 32 + ((lane >> 4) << 3) + j;
    float v = (n < 160) ? w1[n * 320 + k] : wt[(n - 160) * 320 + k];
    dst[i] = f2bf(v);
}

__global__ void pack_w2(const float* __restrict__ w2, unsigned short* __restrict__ dst) {
    int i = blockIdx.x * 256 + threadIdx.x;
    if (i >= 160 * 160) return;
    int j = i & 7;
    int lane = (i >> 3) & 63;
    int r = i >> 9;
    int kb = r % 5;
    int t = r / 5;
    int n = t * 16 + (lane & 15);
    int k = kb * 32 + ((lane >> 4) << 3) + j;
    dst[i] = f2bf(w2[n * 160 + k]);
}

// 32 rows/block, 256 threads (4 waves). wave -> (ms = wave&1 rows half, ns = wave>>1 cols half).
// GEMM1: wave = 16 rows x 160 cols -> acc 40 regs; ns=0 waves own all h1 cols (GN1 wave-local),
// ns=1 waves park ht. GEMM2: wave = 16 rows x 80 cols; GN2 via one LDS stats exchange.
// X tile in LDS unpadded with XOR-granule swizzle (16B granule g' = g ^ (row&7)).
__global__ __launch_bounds__(256, 4) void fused_kernel(
    const float* __restrict__ actors, const float* __restrict__ paths,
    const float* __restrict__ Z_act, const float* __restrict__ Z_pat,
    const int* __restrict__ u,
    const unsigned short* __restrict__ pB1, const unsigned short* __restrict__ pB2,
    const float* __restrict__ g1w, const float* __restrict__ g1b,
    const float* __restrict__ g2w, const float* __restrict__ g2b,
    const float* __restrict__ wh, const float* __restrict__ bh,
    float* __restrict__ out)
{
    // LDS: [0,20480) lX (32 x 320 bf16, swizzled). Aliased after GEMM1:
    // [0,10752) lH1 (32 x HP), [10752,20992) lHT flat, [20992,21760) stats.
    __shared__ __align__(16) char smem[21760];
    unsigned short* lX  = (unsigned short*)smem;
    unsigned short* lH1 = (unsigned short*)smem;
    unsigned short* lHT = (unsigned short*)(smem + 10752);
    float* sS = (float*)(smem + 20992);   // [2][32] sums
    float* sQ = sS + 64;                  // [2][32] sumsq
    float* sD = sS + 128;                 // [2][32] head-dot partials

    const int tid  = threadIdx.x;
    const int wave = tid >> 6;
    const int lane = tid & 63;
    const int quad = lane >> 4;
    const int l15  = lane & 15;
    const int row0 = blockIdx.x * 32;
    const int ms = wave & 1;      // rows half: ms*16 .. ms*16+16
    const int ns = wave >> 1;     // cols half

    // ================= staging (phase-split, 5+5 per thread) =================
    float4 vD[5], vG[5];
    int uv[5];
    #pragma unroll
    for (int i = 0; i < 5; i++) {            // direct loads (k<160) + u
        int f = i * 256 + tid;
        int r = f / 40, q = f - r * 40;
        const float* src = (q < 32) ? (paths + (size_t)(row0 + r) * 128 + q * 4)
                                    : (Z_pat + (size_t)(row0 + r) * 32 + (q - 32) * 4);
        vD[i] = *(const float4*)src;
        uv[i] = u[row0 + r];
    }
    #pragma unroll
    for (int i = 0; i < 5; i++) {            // gather loads (k>=160)
        int f = i * 256 + tid;
        int q = f % 40;
        int un = uv[i];
        const float* src = (q < 32) ? (actors + (size_t)un * 128 + q * 4)
                                    : (Z_act + (size_t)un * 32 + (q - 32) * 4);
        vG[i] = *(const float4*)src;
    }
    #pragma unroll
    for (int i = 0; i < 5; i++) {            // convert + swizzled LDS write (direct)
        int f = i * 256 + tid;
        int r = f / 40, q = f - r * 40;
        int g = q >> 1, sub = q & 1;
        int addr = r * 320 + (((g ^ (r & 7)) << 3) + (sub << 2));
        ushort4 sv;
        sv.x = f2bf(vD[i].x); sv.y = f2bf(vD[i].y); sv.z = f2bf(vD[i].z); sv.w = f2bf(vD[i].w);
        *(ushort4*)(lX + addr) = sv;
    }
    #pragma unroll
    for (int i = 0; i < 5; i++) {            // convert + swizzled LDS write (gather)
        int f = i * 256 + tid;
        int r = f / 40, q = f - r * 40;
        int g = 20 + (q >> 1), sub = q & 1;
        int addr = r * 320 + (((g ^ (r & 7)) << 3) + (sub << 2));
        ushort4 sv;
        sv.x = f2bf(vG[i].x); sv.y = f2bf(vG[i].y); sv.z = f2bf(vG[i].z); sv.w = f2bf(vG[i].w);
        *(ushort4*)(lX + addr) = sv;
    }
    __syncthreads();

    // ================= GEMM1: wave computes rows[ms*16,+16) x cols[ns*160,+160) =================
    floatx4 fzero = {0.f, 0.f, 0.f, 0.f};
    floatx4 acc[10];
    #pragma unroll
    for (int j = 0; j < 10; j++) acc[j] = fzero;

    const int arow = ms * 16 + l15;
    #pragma unroll
    for (int kb = 0; kb < 10; kb++) {
        short8 a = *(const short8*)(lX + arow * 320 + (((kb * 4 + quad) ^ (arow & 7)) << 3));
        short8 b[5];
        #pragma unroll
        for (int ti = 0; ti < 5; ti++)
            b[ti] = *(const short8*)(pB1 + ((size_t)((ns * 10 + ti) * 10 + kb) * 64 + lane) * 8);
        #pragma unroll
        for (int ti = 0; ti < 5; ti++)
            acc[ti] = __builtin_amdgcn_mfma_f32_16x16x32_bf16(a, b[ti], acc[ti], 0, 0, 0);
        #pragma unroll
        for (int ti = 0; ti < 5; ti++)
            b[ti] = *(const short8*)(pB1 + ((size_t)((ns * 10 + 5 + ti) * 10 + kb) * 64 + lane) * 8);
        #pragma unroll
        for (int ti = 0; ti < 5; ti++)
            acc[5 + ti] = __builtin_amdgcn_mfma_f32_16x16x32_bf16(a, b[ti], acc[5 + ti], 0, 0, 0);
    }
    __syncthreads();   // lX reads done; safe to overwrite

    // ================= GN1 (ns=0 waves, wave-local) / park ht (ns=1 waves) =================
    if (ns == 0) {
        float s[4], q2[4];
        #pragma unroll
        for (int r = 0; r < 4; r++) {
            float sv = 0.f, qv = 0.f;
            #pragma unroll
            for (int ti = 0; ti < 10; ti++) {
                float v = acc[ti][r];
                sv += v; qv += v * v;
            }
            s[r] = sv; q2[r] = qv;
        }
        #pragma unroll
        for (int off = 1; off <= 8; off <<= 1)
            #pragma unroll
            for (int r = 0; r < 4; r++) {
                s[r]  += __shfl_xor(s[r],  off, 64);
                q2[r] += __shfl_xor(q2[r], off, 64);
            }
        float gw[10], gb[10];
        #pragma unroll
        for (int ti = 0; ti < 10; ti++) {
            int n = ti * 16 + l15;
            gw[ti] = g1w[n]; gb[ti] = g1b[n];
        }
        #pragma unroll
        for (int r = 0; r < 4; r++) {
            float mu = s[r] * (1.f / 160.f);
            float var = q2[r] * (1.f / 160.f) - mu * mu;
            float rs = rsqrtf(var + 1e-5f);
            int m = ms * 16 + quad * 4 + r;
            #pragma unroll
            for (int ti = 0; ti < 10; ti++) {
                float v = (acc[ti][r] - mu) * rs * gw[ti] + gb[ti];
                v = fmaxf(v, 0.f);
                lH1[m * HP + ti * 16 + l15] = f2bf(v);
            }
        }
    } else {
        #pragma unroll
        for (int ti = 0; ti < 10; ti++)
            #pragma unroll
            for (int r = 0; r < 4; r++)
                lHT[(((ms * 10 + ti) * 4 + r) << 6) + lane] = f2bf(acc[ti][r]);
    }
    __syncthreads();

    // ================= GEMM2: wave = rows[ms*16,+16) x cols[ns*80,+80) =================
    floatx4 acc2[5];
    #pragma unroll
    for (int j = 0; j < 5; j++) acc2[j] = fzero;
    #pragma unroll
    for (int kb = 0; kb < 5; kb++) {
        short8 a = *(const short8*)(lH1 + (ms * 16 + l15) * HP + kb * 32 + quad * 8);
        short8 b[5];
        #pragma unroll
        for (int ti = 0; ti < 5; ti++)
            b[ti] = *(const short8*)(pB2 + ((size_t)((ns * 5 + ti) * 5 + kb) * 64 + lane) * 8);
        #pragma unroll
        for (int ti = 0; ti < 5; ti++)
            acc2[ti] = __builtin_amdgcn_mfma_f32_16x16x32_bf16(a, b[ti], acc2[ti], 0, 0, 0);
    }

    // ================= GN2 partial stats + exchange =================
    {
        float s[4], q2[4];
        #pragma unroll
        for (int r = 0; r < 4; r++) {
            float sv = 0.f, qv = 0.f;
            #pragma unroll
            for (int ti = 0; ti < 5; ti++) {
                float v = acc2[ti][r];
                sv += v; qv += v * v;
            }
            s[r] = sv; q2[r] = qv;
        }
        #pragma unroll
        for (int off = 1; off <= 8; off <<= 1)
            #pragma unroll
            for (int r = 0; r < 4; r++) {
                s[r]  += __shfl_xor(s[r],  off, 64);
                q2[r] += __shfl_xor(q2[r], off, 64);
            }
        if (l15 == 0) {
            #pragma unroll
            for (int r = 0; r < 4; r++) {
                int m = ms * 16 + quad * 4 + r;
                sS[ns * 32 + m] = s[r];
                sQ[ns * 32 + m] = q2[r];
            }
        }
    }
    __syncthreads();

    // ================= GN2 apply + skip(ht) + ReLU + head-dot partial =================
    {
        float g2wv[5], g2bv[5], whv[5];
        #pragma unroll
        for (int ti = 0; ti < 5; ti++) {
            int n = ns * 80 + ti * 16 + l15;
            g2wv[ti] = g2w[n]; g2bv[ti] = g2b[n]; whv[ti] = wh[n];
        }
        float dp[4];
        #pragma unroll
        for (int r = 0; r < 4; r++) {
            int m = ms * 16 + quad * 4 + r;
            float ts = sS[m] + sS[32 + m];
            float tq = sQ[m] + sQ[32 + m];
            float mu = ts * (1.f / 160.f);
            float var = tq * (1.f / 160.f) - mu * mu;
            float rs = rsqrtf(var + 1e-5f);
            float d = 0.f;
            #pragma unroll
            for (int ti = 0; ti < 5; ti++) {
                float v = (acc2[ti][r] - mu) * rs * g2wv[ti] + g2bv[ti];
                v += bf2f(lHT[(((ms * 10 + ns * 5 + ti) * 4 + r) << 6) + lane]);
                v = fmaxf(v, 0.f);
                d += v * whv[ti];
            }
            dp[r] = d;
        }
        #pragma unroll
        for (int off = 1; off <= 8; off <<= 1)
            #pragma unroll
            for (int r = 0; r < 4; r++) dp[r] += __shfl_xor(dp[r], off, 64);
        if (l15 == 0) {
            #pragma unroll
            for (int r = 0; r < 4; r++)
                sD[ns * 32 + ms * 16 + quad * 4 + r] = dp[r];
        }
    }
    __syncthreads();
    if (tid < 32) out[row0 + tid] = sD[tid] + sD[32 + tid] + bh[0];
}

extern "C" void kernel_launch(void* const* d_in, const int* in_sizes, int n_in,
                              void* d_out, int out_size, void* d_ws, size_t ws_size,
                              hipStream_t stream) {
    const float* actors = (const float*)d_in[0];
    const float* paths  = (const float*)d_in[1];
    const float* Z_act  = (const float*)d_in[2];
    const float* Z_pat  = (const float*)d_in[3];
    const int*   u      = (const int*)d_in[4];
    const float* w1     = (const float*)d_in[5];
    const float* w2     = (const float*)d_in[6];
    const float* wt     = (const float*)d_in[7];
    const float* g1w    = (const float*)d_in[8];
    const float* g1b    = (const float*)d_in[9];
    const float* g2w    = (const float*)d_in[10];
    const float* g2b    = (const float*)d_in[11];
    const float* wh     = (const float*)d_in[12];
    const float* bh     = (const float*)d_in[13];
    float* out = (float*)d_out;

    unsigned short* pB1 = (unsigned short*)d_ws;
    unsigned short* pB2 = pB1 + 320 * 320;

    hipLaunchKernelGGL(pack_wc, dim3(400), dim3(256), 0, stream, w1, wt, pB1);
    hipLaunchKernelGGL(pack_w2, dim3(100), dim3(256), 0, stream, w2, pB2);
    hipLaunchKernelGGL(fused_kernel, dim3(400000 / 32), dim3(256), 0, stream,
                       actors, paths, Z_act, Z_pat, u, pB1, pB2,
                       g1w, g1b, g2w, g2b, wh, bh, out);
}